// Round 1
// baseline (2812.139 us; speedup 1.0000x reference)
//
#include <hip/hip_runtime.h>

#define D 128
#define BM 32
#define LDZ 132  // 128 + 4 pad; row stride 528 B = multiple of 16 -> float4-aligned

// ---------------- zero the aggregation buffer ----------------
__global__ __launch_bounds__(256) void gin_zero_kernel(float4* __restrict__ p, int n4) {
    int i = blockIdx.x * 256 + threadIdx.x;
    if (i < n4) p[i] = make_float4(0.f, 0.f, 0.f, 0.f);
}

// ---------------- scatter-add aggregation ----------------
// One thread per (edge, 4-float chunk): 32 chunks per edge.
__global__ __launch_bounds__(256) void gin_scatter_kernel(
    const float* __restrict__ x, const void* __restrict__ ei_raw,
    float* __restrict__ agg, int E)
{
    long long tid = (long long)blockIdx.x * 256 + threadIdx.x;
    int e = (int)(tid >> 5);
    if (e >= E) return;
    int c = (int)(tid & 31);

    const int*       ei32 = (const int*)ei_raw;
    const long long* ei64 = (const long long*)ei_raw;
    // dtype hedge: for int64 input the odd 32-bit words of the first values are 0
    bool is64 = ((ei32[1] | ei32[3] | ei32[5] | ei32[7]) == 0);

    long long dst, src;
    if (is64) { dst = ei64[e]; src = ei64[E + e]; }
    else      { dst = (long long)ei32[e]; src = (long long)ei32[E + e]; }

    float4 v = reinterpret_cast<const float4*>(x + src * D)[c];
    float* p = agg + dst * D + (long long)c * 4;
    atomicAdd(p + 0, v.x);
    atomicAdd(p + 1, v.y);
    atomicAdd(p + 2, v.z);
    atomicAdd(p + 3, v.w);
}

// ---------------- fused (1+eps)x + agg -> MLP(relu) -> out ----------------
// 256 threads: jg = tid&31 owns 4 output features, ng = tid>>5 owns 4 nodes.
// Works in-place when agg == out (each block reads only its own 32 rows, all
// reads complete before the final writes).
__global__ __launch_bounds__(256) void gin_mlp_kernel(
    const float* __restrict__ x, const float* __restrict__ agg,
    const float* __restrict__ epsp,
    const float* __restrict__ W1, const float* __restrict__ b1,
    const float* __restrict__ W2, const float* __restrict__ b2,
    float* __restrict__ out)
{
    __shared__ float Z[BM][LDZ];
    __shared__ float H[BM][LDZ];

    const int tid = threadIdx.x;
    const int jg  = tid & 31;
    const int ng  = tid >> 5;
    const long long n0 = (long long)blockIdx.x * BM;
    const float epsv = 1.0f + epsp[0];

    // stage Z = (1+eps)*x + agg for this block's 32 nodes
    for (int i = tid; i < BM * (D / 4); i += 256) {
        int n = i >> 5;
        int c = i & 31;
        float4 xv = reinterpret_cast<const float4*>(x   + (n0 + n) * D)[c];
        float4 av = reinterpret_cast<const float4*>(agg + (n0 + n) * D)[c];
        float4 z;
        z.x = fmaf(epsv, xv.x, av.x);
        z.y = fmaf(epsv, xv.y, av.y);
        z.z = fmaf(epsv, xv.z, av.z);
        z.w = fmaf(epsv, xv.w, av.w);
        *reinterpret_cast<float4*>(&Z[n][c * 4]) = z;
    }
    __syncthreads();

    float acc[4][4];

    // ---- matmul 1: H = relu(Z @ W1 + b1) ----
    {
        float4 bv = reinterpret_cast<const float4*>(b1)[jg];
        #pragma unroll
        for (int i = 0; i < 4; ++i) {
            acc[i][0] = bv.x; acc[i][1] = bv.y; acc[i][2] = bv.z; acc[i][3] = bv.w;
        }
    }
    for (int k = 0; k < D; k += 4) {
        float4 wv[4];
        #pragma unroll
        for (int kk = 0; kk < 4; ++kk)
            wv[kk] = reinterpret_cast<const float4*>(W1 + (k + kk) * D)[jg];
        const float* wf = reinterpret_cast<const float*>(wv);
        #pragma unroll
        for (int i = 0; i < 4; ++i) {
            float4 zv = *reinterpret_cast<const float4*>(&Z[ng * 4 + i][k]);
            float zf[4] = {zv.x, zv.y, zv.z, zv.w};
            #pragma unroll
            for (int kk = 0; kk < 4; ++kk)
                #pragma unroll
                for (int jj = 0; jj < 4; ++jj)
                    acc[i][jj] = fmaf(zf[kk], wf[kk * 4 + jj], acc[i][jj]);
        }
    }
    #pragma unroll
    for (int i = 0; i < 4; ++i) {
        float4 h;
        h.x = fmaxf(acc[i][0], 0.f);
        h.y = fmaxf(acc[i][1], 0.f);
        h.z = fmaxf(acc[i][2], 0.f);
        h.w = fmaxf(acc[i][3], 0.f);
        *reinterpret_cast<float4*>(&H[ng * 4 + i][jg * 4]) = h;
    }
    __syncthreads();

    // ---- matmul 2: out = H @ W2 + b2 ----
    {
        float4 bv = reinterpret_cast<const float4*>(b2)[jg];
        #pragma unroll
        for (int i = 0; i < 4; ++i) {
            acc[i][0] = bv.x; acc[i][1] = bv.y; acc[i][2] = bv.z; acc[i][3] = bv.w;
        }
    }
    for (int k = 0; k < D; k += 4) {
        float4 wv[4];
        #pragma unroll
        for (int kk = 0; kk < 4; ++kk)
            wv[kk] = reinterpret_cast<const float4*>(W2 + (k + kk) * D)[jg];
        const float* wf = reinterpret_cast<const float*>(wv);
        #pragma unroll
        for (int i = 0; i < 4; ++i) {
            float4 hv = *reinterpret_cast<const float4*>(&H[ng * 4 + i][k]);
            float hf[4] = {hv.x, hv.y, hv.z, hv.w};
            #pragma unroll
            for (int kk = 0; kk < 4; ++kk)
                #pragma unroll
                for (int jj = 0; jj < 4; ++jj)
                    acc[i][jj] = fmaf(hf[kk], wf[kk * 4 + jj], acc[i][jj]);
        }
    }
    #pragma unroll
    for (int i = 0; i < 4; ++i) {
        float4 o;
        o.x = acc[i][0]; o.y = acc[i][1]; o.z = acc[i][2]; o.w = acc[i][3];
        reinterpret_cast<float4*>(out + (n0 + ng * 4 + i) * D)[jg] = o;
    }
}

extern "C" void kernel_launch(void* const* d_in, const int* in_sizes, int n_in,
                              void* d_out, int out_size, void* d_ws, size_t ws_size,
                              hipStream_t stream) {
    const float* x   = (const float*)d_in[0];
    const void*  ei  = d_in[1];
    const float* eps = (const float*)d_in[3];
    const float* W1  = (const float*)d_in[4];
    const float* b1  = (const float*)d_in[5];
    const float* W2  = (const float*)d_in[6];
    const float* b2  = (const float*)d_in[7];
    float* out = (float*)d_out;

    const int N = in_sizes[0] / D;       // 100000
    const int E = in_sizes[1] / 2;       // 1600000

    // agg buffer: prefer workspace; fall back to in-place in d_out (safe: the
    // MLP kernel reads exactly the rows it later writes, within one block).
    float* agg = (ws_size >= (size_t)N * D * sizeof(float)) ? (float*)d_ws : out;

    const int n4 = N * D / 4;
    gin_zero_kernel<<<(n4 + 255) / 256, 256, 0, stream>>>((float4*)agg, n4);

    const long long total = (long long)E * 32;
    gin_scatter_kernel<<<(int)((total + 255) / 256), 256, 0, stream>>>(x, ei, agg, E);

    gin_mlp_kernel<<<N / BM, 256, 0, stream>>>(x, agg, eps, W1, b1, W2, b2, out);
}

// Round 2
// 372.510 us; speedup vs baseline: 7.5492x; 7.5492x over previous
//
#include <hip/hip_runtime.h>

#define D 128
#define BM 32
#define LDZ 132      // 128 + 4 pad floats; row stride 528 B (16B-aligned)
#define SCAN_B 1024  // elements per scan block

// ---------- edge-index dtype hedge (int64 vs int32), wave-uniform ----------
__device__ __forceinline__ bool ei_is64(const int* ei32) {
    // for int64 indices (< 2^32) the high words of the first values are 0
    return ((ei32[1] | ei32[3] | ei32[5] | ei32[7]) == 0);
}

// ---------------- zero int region ----------------
__global__ __launch_bounds__(256) void gin_zero_i(int* __restrict__ p, int n) {
    int i = blockIdx.x * 256 + threadIdx.x;
    if (i < n) p[i] = 0;
}

// ---------------- histogram of destinations ----------------
__global__ __launch_bounds__(256) void gin_hist(const void* __restrict__ ei_raw,
                                                int* __restrict__ cnt, int E) {
    int e = blockIdx.x * 256 + threadIdx.x;
    if (e >= E) return;
    const int* ei32 = (const int*)ei_raw;
    const long long* ei64 = (const long long*)ei_raw;
    int dst = ei_is64(ei32) ? (int)ei64[e] : ei32[e];
    atomicAdd(&cnt[dst], 1);
}

// ---------------- hierarchical exclusive scan ----------------
__global__ __launch_bounds__(256) void gin_scan1(const int* __restrict__ cnt,
                                                 int* __restrict__ off,
                                                 int* __restrict__ bsum, int N) {
    __shared__ int ts[256];
    int tid = threadIdx.x;
    int base = blockIdx.x * SCAN_B + tid * 4;
    int v[4]; int s = 0;
    #pragma unroll
    for (int j = 0; j < 4; ++j) { int idx = base + j; v[j] = (idx < N) ? cnt[idx] : 0; s += v[j]; }
    ts[tid] = s;
    __syncthreads();
    for (int d = 1; d < 256; d <<= 1) {
        int t = (tid >= d) ? ts[tid - d] : 0;
        __syncthreads();
        ts[tid] += t;
        __syncthreads();
    }
    int excl = ts[tid] - s;
    if (tid == 255) bsum[blockIdx.x] = ts[255];
    int run = excl;
    #pragma unroll
    for (int j = 0; j < 4; ++j) { int idx = base + j; if (idx < N) off[idx] = run; run += v[j]; }
}

__global__ void gin_scan2(int* __restrict__ bsum, int nb) {
    if (threadIdx.x == 0) {
        int run = 0;
        for (int b = 0; b < nb; ++b) { int t = bsum[b]; bsum[b] = run; run += t; }
    }
}

__global__ __launch_bounds__(256) void gin_scan3(int* __restrict__ off,
                                                 const int* __restrict__ bsum, int N) {
    int i = blockIdx.x * 256 + threadIdx.x;
    if (i < N) off[i] += bsum[i >> 10];  // SCAN_B = 1024
}

// ---------------- fill buckets with source indices ----------------
__global__ __launch_bounds__(256) void gin_fill(const void* __restrict__ ei_raw,
                                                const int* __restrict__ off,
                                                int* __restrict__ cur,
                                                int* __restrict__ bucket, int E) {
    int e = blockIdx.x * 256 + threadIdx.x;
    if (e >= E) return;
    const int* ei32 = (const int*)ei_raw;
    const long long* ei64 = (const long long*)ei_raw;
    int dst, src;
    if (ei_is64(ei32)) { dst = (int)ei64[e]; src = (int)ei64[E + e]; }
    else               { dst = ei32[e];      src = ei32[E + e]; }
    int p = atomicAdd(&cur[dst], 1);
    bucket[off[dst] + p] = src;
}

// ---------------- fused gather-sum + (1+eps)x + MLP ----------------
__global__ __launch_bounds__(256) void gin_fused(
    const float* __restrict__ x, const float* __restrict__ epsp,
    const float* __restrict__ W1, const float* __restrict__ b1,
    const float* __restrict__ W2, const float* __restrict__ b2,
    const int* __restrict__ off, const int* __restrict__ cnt,
    const int* __restrict__ bucket, float* __restrict__ out)
{
    __shared__ float Z[BM][LDZ];
    __shared__ float H[BM][LDZ];

    const int tid  = threadIdx.x;
    const int lane = tid & 31;   // feature chunk (float4) / output feature group
    const int grp  = tid >> 5;   // 8 groups of 32 lanes
    const long long n0 = (long long)blockIdx.x * BM;
    const float epsv = 1.0f + epsp[0];

    // ---- gather: Z[n] = (1+eps)*x[n] + sum_{e in bucket(n)} x[src(e)] ----
    for (int nn = grp; nn < BM; nn += 8) {
        long long node = n0 + nn;
        float4 acc = reinterpret_cast<const float4*>(x + node * D)[lane];
        acc.x *= epsv; acc.y *= epsv; acc.z *= epsv; acc.w *= epsv;
        int start = off[node];
        int deg   = cnt[node];
        int j = 0;
        for (; j + 4 <= deg; j += 4) {
            int s0 = bucket[start + j + 0];
            int s1 = bucket[start + j + 1];
            int s2 = bucket[start + j + 2];
            int s3 = bucket[start + j + 3];
            float4 v0 = reinterpret_cast<const float4*>(x + (long long)s0 * D)[lane];
            float4 v1 = reinterpret_cast<const float4*>(x + (long long)s1 * D)[lane];
            float4 v2 = reinterpret_cast<const float4*>(x + (long long)s2 * D)[lane];
            float4 v3 = reinterpret_cast<const float4*>(x + (long long)s3 * D)[lane];
            acc.x += (v0.x + v1.x) + (v2.x + v3.x);
            acc.y += (v0.y + v1.y) + (v2.y + v3.y);
            acc.z += (v0.z + v1.z) + (v2.z + v3.z);
            acc.w += (v0.w + v1.w) + (v2.w + v3.w);
        }
        for (; j < deg; ++j) {
            int s = bucket[start + j];
            float4 v = reinterpret_cast<const float4*>(x + (long long)s * D)[lane];
            acc.x += v.x; acc.y += v.y; acc.z += v.z; acc.w += v.w;
        }
        *reinterpret_cast<float4*>(&Z[nn][lane * 4]) = acc;
    }
    __syncthreads();

    const int jg = lane;  // 4 output features per lane
    const int ng = grp;   // 4 nodes per group
    float acc[4][4];

    // ---- matmul 1: H = relu(Z @ W1 + b1) ----
    {
        float4 bv = reinterpret_cast<const float4*>(b1)[jg];
        #pragma unroll
        for (int i = 0; i < 4; ++i) {
            acc[i][0] = bv.x; acc[i][1] = bv.y; acc[i][2] = bv.z; acc[i][3] = bv.w;
        }
    }
    for (int k = 0; k < D; k += 4) {
        float4 wv[4];
        #pragma unroll
        for (int kk = 0; kk < 4; ++kk)
            wv[kk] = reinterpret_cast<const float4*>(W1 + (k + kk) * D)[jg];
        const float* wf = reinterpret_cast<const float*>(wv);
        #pragma unroll
        for (int i = 0; i < 4; ++i) {
            float4 zv = *reinterpret_cast<const float4*>(&Z[ng * 4 + i][k]);
            float zf[4] = {zv.x, zv.y, zv.z, zv.w};
            #pragma unroll
            for (int kk = 0; kk < 4; ++kk)
                #pragma unroll
                for (int jj = 0; jj < 4; ++jj)
                    acc[i][jj] = fmaf(zf[kk], wf[kk * 4 + jj], acc[i][jj]);
        }
    }
    #pragma unroll
    for (int i = 0; i < 4; ++i) {
        float4 h;
        h.x = fmaxf(acc[i][0], 0.f);
        h.y = fmaxf(acc[i][1], 0.f);
        h.z = fmaxf(acc[i][2], 0.f);
        h.w = fmaxf(acc[i][3], 0.f);
        *reinterpret_cast<float4*>(&H[ng * 4 + i][jg * 4]) = h;
    }
    __syncthreads();

    // ---- matmul 2: out = H @ W2 + b2 ----
    {
        float4 bv = reinterpret_cast<const float4*>(b2)[jg];
        #pragma unroll
        for (int i = 0; i < 4; ++i) {
            acc[i][0] = bv.x; acc[i][1] = bv.y; acc[i][2] = bv.z; acc[i][3] = bv.w;
        }
    }
    for (int k = 0; k < D; k += 4) {
        float4 wv[4];
        #pragma unroll
        for (int kk = 0; kk < 4; ++kk)
            wv[kk] = reinterpret_cast<const float4*>(W2 + (k + kk) * D)[jg];
        const float* wf = reinterpret_cast<const float*>(wv);
        #pragma unroll
        for (int i = 0; i < 4; ++i) {
            float4 hv = *reinterpret_cast<const float4*>(&H[ng * 4 + i][k]);
            float hf[4] = {hv.x, hv.y, hv.z, hv.w};
            #pragma unroll
            for (int kk = 0; kk < 4; ++kk)
                #pragma unroll
                for (int jj = 0; jj < 4; ++jj)
                    acc[i][jj] = fmaf(hf[kk], wf[kk * 4 + jj], acc[i][jj]);
        }
    }
    #pragma unroll
    for (int i = 0; i < 4; ++i) {
        float4 o;
        o.x = acc[i][0]; o.y = acc[i][1]; o.z = acc[i][2]; o.w = acc[i][3];
        reinterpret_cast<float4*>(out + (n0 + ng * 4 + i) * D)[jg] = o;
    }
}

// ================= fallback (atomic scatter) kernels =================
__global__ __launch_bounds__(256) void gin_zero_f(float4* __restrict__ p, int n4) {
    int i = blockIdx.x * 256 + threadIdx.x;
    if (i < n4) p[i] = make_float4(0.f, 0.f, 0.f, 0.f);
}

__global__ __launch_bounds__(256) void gin_scatter_kernel(
    const float* __restrict__ x, const void* __restrict__ ei_raw,
    float* __restrict__ agg, int E)
{
    long long tid = (long long)blockIdx.x * 256 + threadIdx.x;
    int e = (int)(tid >> 5);
    if (e >= E) return;
    int c = (int)(tid & 31);
    const int* ei32 = (const int*)ei_raw;
    const long long* ei64 = (const long long*)ei_raw;
    long long dst, src;
    if (ei_is64(ei32)) { dst = ei64[e]; src = ei64[E + e]; }
    else               { dst = (long long)ei32[e]; src = (long long)ei32[E + e]; }
    float4 v = reinterpret_cast<const float4*>(x + src * D)[c];
    float* p = agg + dst * D + (long long)c * 4;
    atomicAdd(p + 0, v.x);
    atomicAdd(p + 1, v.y);
    atomicAdd(p + 2, v.z);
    atomicAdd(p + 3, v.w);
}

__global__ __launch_bounds__(256) void gin_mlp_kernel(
    const float* __restrict__ x, const float* __restrict__ agg,
    const float* __restrict__ epsp,
    const float* __restrict__ W1, const float* __restrict__ b1,
    const float* __restrict__ W2, const float* __restrict__ b2,
    float* __restrict__ out)
{
    __shared__ float Z[BM][LDZ];
    __shared__ float H[BM][LDZ];
    const int tid = threadIdx.x;
    const int jg  = tid & 31;
    const int ng  = tid >> 5;
    const long long n0 = (long long)blockIdx.x * BM;
    const float epsv = 1.0f + epsp[0];

    for (int i = tid; i < BM * (D / 4); i += 256) {
        int n = i >> 5;
        int c = i & 31;
        float4 xv = reinterpret_cast<const float4*>(x   + (n0 + n) * D)[c];
        float4 av = reinterpret_cast<const float4*>(agg + (n0 + n) * D)[c];
        float4 z;
        z.x = fmaf(epsv, xv.x, av.x);
        z.y = fmaf(epsv, xv.y, av.y);
        z.z = fmaf(epsv, xv.z, av.z);
        z.w = fmaf(epsv, xv.w, av.w);
        *reinterpret_cast<float4*>(&Z[n][c * 4]) = z;
    }
    __syncthreads();

    float acc[4][4];
    {
        float4 bv = reinterpret_cast<const float4*>(b1)[jg];
        #pragma unroll
        for (int i = 0; i < 4; ++i) {
            acc[i][0] = bv.x; acc[i][1] = bv.y; acc[i][2] = bv.z; acc[i][3] = bv.w;
        }
    }
    for (int k = 0; k < D; k += 4) {
        float4 wv[4];
        #pragma unroll
        for (int kk = 0; kk < 4; ++kk)
            wv[kk] = reinterpret_cast<const float4*>(W1 + (k + kk) * D)[jg];
        const float* wf = reinterpret_cast<const float*>(wv);
        #pragma unroll
        for (int i = 0; i < 4; ++i) {
            float4 zv = *reinterpret_cast<const float4*>(&Z[ng * 4 + i][k]);
            float zf[4] = {zv.x, zv.y, zv.z, zv.w};
            #pragma unroll
            for (int kk = 0; kk < 4; ++kk)
                #pragma unroll
                for (int jj = 0; jj < 4; ++jj)
                    acc[i][jj] = fmaf(zf[kk], wf[kk * 4 + jj], acc[i][jj]);
        }
    }
    #pragma unroll
    for (int i = 0; i < 4; ++i) {
        float4 h;
        h.x = fmaxf(acc[i][0], 0.f);
        h.y = fmaxf(acc[i][1], 0.f);
        h.z = fmaxf(acc[i][2], 0.f);
        h.w = fmaxf(acc[i][3], 0.f);
        *reinterpret_cast<float4*>(&H[ng * 4 + i][jg * 4]) = h;
    }
    __syncthreads();

    {
        float4 bv = reinterpret_cast<const float4*>(b2)[jg];
        #pragma unroll
        for (int i = 0; i < 4; ++i) {
            acc[i][0] = bv.x; acc[i][1] = bv.y; acc[i][2] = bv.z; acc[i][3] = bv.w;
        }
    }
    for (int k = 0; k < D; k += 4) {
        float4 wv[4];
        #pragma unroll
        for (int kk = 0; kk < 4; ++kk)
            wv[kk] = reinterpret_cast<const float4*>(W2 + (k + kk) * D)[jg];
        const float* wf = reinterpret_cast<const float*>(wv);
        #pragma unroll
        for (int i = 0; i < 4; ++i) {
            float4 hv = *reinterpret_cast<const float4*>(&H[ng * 4 + i][k]);
            float hf[4] = {hv.x, hv.y, hv.z, hv.w};
            #pragma unroll
            for (int kk = 0; kk < 4; ++kk)
                #pragma unroll
                for (int jj = 0; jj < 4; ++jj)
                    acc[i][jj] = fmaf(hf[kk], wf[kk * 4 + jj], acc[i][jj]);
        }
    }
    #pragma unroll
    for (int i = 0; i < 4; ++i) {
        float4 o;
        o.x = acc[i][0]; o.y = acc[i][1]; o.z = acc[i][2]; o.w = acc[i][3];
        reinterpret_cast<float4*>(out + (n0 + ng * 4 + i) * D)[jg] = o;
    }
}

extern "C" void kernel_launch(void* const* d_in, const int* in_sizes, int n_in,
                              void* d_out, int out_size, void* d_ws, size_t ws_size,
                              hipStream_t stream) {
    const float* x   = (const float*)d_in[0];
    const void*  ei  = d_in[1];
    const float* eps = (const float*)d_in[3];
    const float* W1  = (const float*)d_in[4];
    const float* b1  = (const float*)d_in[5];
    const float* W2  = (const float*)d_in[6];
    const float* b2  = (const float*)d_in[7];
    float* out = (float*)d_out;

    const int N = in_sizes[0] / D;   // 100000
    const int E = in_sizes[1] / 2;   // 1600000
    const int nb = (N + SCAN_B - 1) / SCAN_B;
    const int nb_pad = (nb + 127) & ~127;

    // ws layout: cnt[N] | off[N+1] | cur[N] | bsum[nb_pad] | bucket[E]
    size_t need = ((size_t)3 * N + 1 + nb_pad + E) * sizeof(int);

    if (ws_size >= need) {
        int* cnt    = (int*)d_ws;
        int* off    = cnt + N;
        int* cur    = off + N + 1;
        int* bsum   = cur + N;
        int* bucket = bsum + nb_pad;

        int zn = 3 * N + 1 + nb_pad;
        gin_zero_i<<<(zn + 255) / 256, 256, 0, stream>>>(cnt, zn);
        gin_hist<<<(E + 255) / 256, 256, 0, stream>>>(ei, cnt, E);
        gin_scan1<<<nb, 256, 0, stream>>>(cnt, off, bsum, N);
        gin_scan2<<<1, 64, 0, stream>>>(bsum, nb);
        gin_scan3<<<(N + 255) / 256, 256, 0, stream>>>(off, bsum, N);
        gin_fill<<<(E + 255) / 256, 256, 0, stream>>>(ei, off, cur, bucket, E);
        gin_fused<<<(N + BM - 1) / BM, 256, 0, stream>>>(x, eps, W1, b1, W2, b2,
                                                         off, cnt, bucket, out);
    } else {
        // fallback: atomic scatter into out, then in-place MLP
        float* agg = out;
        const int n4 = N * D / 4;
        gin_zero_f<<<(n4 + 255) / 256, 256, 0, stream>>>((float4*)agg, n4);
        const long long total = (long long)E * 32;
        gin_scatter_kernel<<<(int)((total + 255) / 256), 256, 0, stream>>>(x, ei, agg, E);
        gin_mlp_kernel<<<N / BM, 256, 0, stream>>>(x, agg, eps, W1, b1, W2, b2, out);
    }
}

// Round 3
// 327.943 us; speedup vs baseline: 8.5751x; 1.1359x over previous
//
#include <hip/hip_runtime.h>

#define D 128
#define BM 32
#define LDZ 132      // 128 + 4 pad floats; row stride 528 B (16B-aligned)
#define SCAN_B 1024

typedef unsigned int uint;
typedef unsigned short ushort;

// ---------- edge-index dtype hedge (int64 vs int32), wave-uniform ----------
__device__ __forceinline__ bool ei_is64(const int* ei32) {
    // for int64 indices (< 2^32) the high words of the first values are 0
    return ((ei32[1] | ei32[3] | ei32[5] | ei32[7]) == 0);
}

__device__ __forceinline__ float b2f(ushort u) {
    return __uint_as_float((uint)u << 16);
}

// ---------------- zero int region ----------------
__global__ __launch_bounds__(256) void gin_zero_i(int* __restrict__ p, int n) {
    int i = blockIdx.x * 256 + threadIdx.x;
    if (i < n) p[i] = 0;
}

// ---------------- x -> bf16 copy (round-to-nearest-even) ----------------
__global__ __launch_bounds__(256) void gin_cvt_bf16(const float4* __restrict__ x4,
                                                    ushort4* __restrict__ xb4, int n4) {
    int i = blockIdx.x * 256 + threadIdx.x;
    if (i >= n4) return;
    float4 v = x4[i];
    uint a = __float_as_uint(v.x), b = __float_as_uint(v.y),
         c = __float_as_uint(v.z), d = __float_as_uint(v.w);
    ushort4 o;
    o.x = (ushort)((a + 0x7fffu + ((a >> 16) & 1u)) >> 16);
    o.y = (ushort)((b + 0x7fffu + ((b >> 16) & 1u)) >> 16);
    o.z = (ushort)((c + 0x7fffu + ((c >> 16) & 1u)) >> 16);
    o.w = (ushort)((d + 0x7fffu + ((d >> 16) & 1u)) >> 16);
    xb4[i] = o;
}

// ---------------- histogram of destinations ----------------
__global__ __launch_bounds__(256) void gin_hist(const void* __restrict__ ei_raw,
                                                int* __restrict__ cnt, int E) {
    int e = blockIdx.x * 256 + threadIdx.x;
    if (e >= E) return;
    const int* ei32 = (const int*)ei_raw;
    const long long* ei64 = (const long long*)ei_raw;
    int dst = ei_is64(ei32) ? (int)ei64[e] : ei32[e];
    atomicAdd(&cnt[dst], 1);
}

// ---------------- per-1024-block exclusive scan (partial) ----------------
__global__ __launch_bounds__(256) void gin_scan1(const int* __restrict__ cnt,
                                                 int* __restrict__ off,
                                                 int* __restrict__ bsum, int N) {
    __shared__ int ts[256];
    int tid = threadIdx.x;
    int base = blockIdx.x * SCAN_B + tid * 4;
    int v[4]; int s = 0;
    #pragma unroll
    for (int j = 0; j < 4; ++j) { int idx = base + j; v[j] = (idx < N) ? cnt[idx] : 0; s += v[j]; }
    ts[tid] = s;
    __syncthreads();
    for (int d = 1; d < 256; d <<= 1) {
        int t = (tid >= d) ? ts[tid - d] : 0;
        __syncthreads();
        ts[tid] += t;
        __syncthreads();
    }
    int excl = ts[tid] - s;
    if (tid == 255) bsum[blockIdx.x] = ts[255];
    int run = excl;
    #pragma unroll
    for (int j = 0; j < 4; ++j) { int idx = base + j; if (idx < N) off[idx] = run; run += v[j]; }
}

// ---------------- parallel scan of block sums (one block) ----------------
__global__ __launch_bounds__(1024) void gin_scan2(int* __restrict__ bsum, int nb) {
    __shared__ int ts[1024];
    int t = threadIdx.x;
    if (nb <= 1024) {
        int v = (t < nb) ? bsum[t] : 0;
        ts[t] = v;
        __syncthreads();
        for (int d = 1; d < 1024; d <<= 1) {
            int u = (t >= d) ? ts[t - d] : 0;
            __syncthreads();
            ts[t] += u;
            __syncthreads();
        }
        if (t < nb) bsum[t] = ts[t] - v;   // exclusive
    } else if (t == 0) {
        int run = 0;
        for (int b = 0; b < nb; ++b) { int v = bsum[b]; bsum[b] = run; run += v; }
    }
}

// ---------------- fill buckets with source indices ----------------
__global__ __launch_bounds__(256) void gin_fill(const void* __restrict__ ei_raw,
                                                const int* __restrict__ off,
                                                const int* __restrict__ bsum,
                                                int* __restrict__ cur,
                                                int* __restrict__ bucket, int E) {
    int e = blockIdx.x * 256 + threadIdx.x;
    if (e >= E) return;
    const int* ei32 = (const int*)ei_raw;
    const long long* ei64 = (const long long*)ei_raw;
    int dst, src;
    if (ei_is64(ei32)) { dst = (int)ei64[e]; src = (int)ei64[E + e]; }
    else               { dst = ei32[e];      src = ei32[E + e]; }
    int p = atomicAdd(&cur[dst], 1);
    bucket[off[dst] + bsum[dst >> 10] + p] = src;
}

// ---------------- fused gather-sum + (1+eps)x + MLP ----------------
template<int BF16>
__global__ __launch_bounds__(256, 8) void gin_fused(
    const float* __restrict__ x, const ushort* __restrict__ xb,
    const float* __restrict__ epsp,
    const float* __restrict__ W1, const float* __restrict__ b1,
    const float* __restrict__ W2, const float* __restrict__ b2,
    const int* __restrict__ off, const int* __restrict__ cnt,
    const int* __restrict__ bsum,
    const int* __restrict__ bucket, float* __restrict__ out)
{
    __shared__ float S[BM][LDZ];   // Z, then reused for H

    const int tid  = threadIdx.x;
    const int lane = tid & 31;   // float4 chunk within a row / output feature group
    const int grp  = tid >> 5;   // 8 groups of 32 lanes
    const long long n0 = (long long)blockIdx.x * BM;
    const float epsv = 1.0f + epsp[0];

    // ---- gather: S[n] = (1+eps)*x[n] + sum_{e in bucket(n)} x[src(e)] ----
    for (int nn = grp; nn < BM; nn += 8) {
        long long node = n0 + nn;
        float4 acc = reinterpret_cast<const float4*>(x + node * D)[lane];
        acc.x *= epsv; acc.y *= epsv; acc.z *= epsv; acc.w *= epsv;
        int start = off[node] + bsum[node >> 10];
        int deg   = cnt[node];
        int j = 0;
        if (BF16) {
            const ushort4* xr = reinterpret_cast<const ushort4*>(xb);
            for (; j + 4 <= deg; j += 4) {
                int s0 = bucket[start + j + 0];
                int s1 = bucket[start + j + 1];
                int s2 = bucket[start + j + 2];
                int s3 = bucket[start + j + 3];
                ushort4 r0 = xr[(long long)s0 * 32 + lane];
                ushort4 r1 = xr[(long long)s1 * 32 + lane];
                ushort4 r2 = xr[(long long)s2 * 32 + lane];
                ushort4 r3 = xr[(long long)s3 * 32 + lane];
                acc.x += (b2f(r0.x) + b2f(r1.x)) + (b2f(r2.x) + b2f(r3.x));
                acc.y += (b2f(r0.y) + b2f(r1.y)) + (b2f(r2.y) + b2f(r3.y));
                acc.z += (b2f(r0.z) + b2f(r1.z)) + (b2f(r2.z) + b2f(r3.z));
                acc.w += (b2f(r0.w) + b2f(r1.w)) + (b2f(r2.w) + b2f(r3.w));
            }
            for (; j < deg; ++j) {
                int s = bucket[start + j];
                ushort4 r = xr[(long long)s * 32 + lane];
                acc.x += b2f(r.x); acc.y += b2f(r.y);
                acc.z += b2f(r.z); acc.w += b2f(r.w);
            }
        } else {
            for (; j + 4 <= deg; j += 4) {
                int s0 = bucket[start + j + 0];
                int s1 = bucket[start + j + 1];
                int s2 = bucket[start + j + 2];
                int s3 = bucket[start + j + 3];
                float4 v0 = reinterpret_cast<const float4*>(x + (long long)s0 * D)[lane];
                float4 v1 = reinterpret_cast<const float4*>(x + (long long)s1 * D)[lane];
                float4 v2 = reinterpret_cast<const float4*>(x + (long long)s2 * D)[lane];
                float4 v3 = reinterpret_cast<const float4*>(x + (long long)s3 * D)[lane];
                acc.x += (v0.x + v1.x) + (v2.x + v3.x);
                acc.y += (v0.y + v1.y) + (v2.y + v3.y);
                acc.z += (v0.z + v1.z) + (v2.z + v3.z);
                acc.w += (v0.w + v1.w) + (v2.w + v3.w);
            }
            for (; j < deg; ++j) {
                int s = bucket[start + j];
                float4 v = reinterpret_cast<const float4*>(x + (long long)s * D)[lane];
                acc.x += v.x; acc.y += v.y; acc.z += v.z; acc.w += v.w;
            }
        }
        *reinterpret_cast<float4*>(&S[nn][lane * 4]) = acc;
    }
    __syncthreads();

    const int jg = lane;  // 4 output features per lane
    const int ng = grp;   // 4 nodes per group
    float acc[4][4];

    // ---- matmul 1: H = relu(Z @ W1 + b1) ----
    {
        float4 bv = reinterpret_cast<const float4*>(b1)[jg];
        #pragma unroll
        for (int i = 0; i < 4; ++i) {
            acc[i][0] = bv.x; acc[i][1] = bv.y; acc[i][2] = bv.z; acc[i][3] = bv.w;
        }
    }
    for (int k = 0; k < D; k += 4) {
        float4 wv[4];
        #pragma unroll
        for (int kk = 0; kk < 4; ++kk)
            wv[kk] = reinterpret_cast<const float4*>(W1 + (k + kk) * D)[jg];
        const float* wf = reinterpret_cast<const float*>(wv);
        #pragma unroll
        for (int i = 0; i < 4; ++i) {
            float4 zv = *reinterpret_cast<const float4*>(&S[ng * 4 + i][k]);
            float zf[4] = {zv.x, zv.y, zv.z, zv.w};
            #pragma unroll
            for (int kk = 0; kk < 4; ++kk)
                #pragma unroll
                for (int jj = 0; jj < 4; ++jj)
                    acc[i][jj] = fmaf(zf[kk], wf[kk * 4 + jj], acc[i][jj]);
        }
    }
    __syncthreads();   // all Z reads complete before overwriting S with H
    #pragma unroll
    for (int i = 0; i < 4; ++i) {
        float4 h;
        h.x = fmaxf(acc[i][0], 0.f);
        h.y = fmaxf(acc[i][1], 0.f);
        h.z = fmaxf(acc[i][2], 0.f);
        h.w = fmaxf(acc[i][3], 0.f);
        *reinterpret_cast<float4*>(&S[ng * 4 + i][jg * 4]) = h;
    }
    __syncthreads();

    // ---- matmul 2: out = H @ W2 + b2 ----
    {
        float4 bv = reinterpret_cast<const float4*>(b2)[jg];
        #pragma unroll
        for (int i = 0; i < 4; ++i) {
            acc[i][0] = bv.x; acc[i][1] = bv.y; acc[i][2] = bv.z; acc[i][3] = bv.w;
        }
    }
    for (int k = 0; k < D; k += 4) {
        float4 wv[4];
        #pragma unroll
        for (int kk = 0; kk < 4; ++kk)
            wv[kk] = reinterpret_cast<const float4*>(W2 + (k + kk) * D)[jg];
        const float* wf = reinterpret_cast<const float*>(wv);
        #pragma unroll
        for (int i = 0; i < 4; ++i) {
            float4 hv = *reinterpret_cast<const float4*>(&S[ng * 4 + i][k]);
            float hf[4] = {hv.x, hv.y, hv.z, hv.w};
            #pragma unroll
            for (int kk = 0; kk < 4; ++kk)
                #pragma unroll
                for (int jj = 0; jj < 4; ++jj)
                    acc[i][jj] = fmaf(hf[kk], wf[kk * 4 + jj], acc[i][jj]);
        }
    }
    #pragma unroll
    for (int i = 0; i < 4; ++i) {
        float4 o;
        o.x = acc[i][0]; o.y = acc[i][1]; o.z = acc[i][2]; o.w = acc[i][3];
        reinterpret_cast<float4*>(out + (n0 + ng * 4 + i) * D)[jg] = o;
    }
}

extern "C" void kernel_launch(void* const* d_in, const int* in_sizes, int n_in,
                              void* d_out, int out_size, void* d_ws, size_t ws_size,
                              hipStream_t stream) {
    const float* x   = (const float*)d_in[0];
    const void*  ei  = d_in[1];
    const float* eps = (const float*)d_in[3];
    const float* W1  = (const float*)d_in[4];
    const float* b1  = (const float*)d_in[5];
    const float* W2  = (const float*)d_in[6];
    const float* b2  = (const float*)d_in[7];
    float* out = (float*)d_out;

    const int N = in_sizes[0] / D;   // 100000
    const int E = in_sizes[1] / 2;   // 1600000
    const int nb = (N + SCAN_B - 1) / SCAN_B;
    const int nb_pad = (nb + 255) & ~255;

    // ws layout: cnt[N] | cur[N] | off[N] | bsum[nb_pad] | bucket[E] | xb[N*D] (bf16)
    size_t ints = (size_t)3 * N + nb_pad + E;
    size_t base_bytes = ints * sizeof(int);
    size_t xb_off = (base_bytes + 15) & ~(size_t)15;
    size_t need_bf16 = xb_off + (size_t)N * D * sizeof(ushort);
    size_t need_fp32 = base_bytes;

    if (ws_size < need_fp32) return;  // cannot happen per prior rounds

    int* cnt    = (int*)d_ws;
    int* cur    = cnt + N;
    int* off    = cur + N;
    int* bsum   = off + N;
    int* bucket = bsum + nb_pad;
    ushort* xb  = (ushort*)((char*)d_ws + xb_off);
    const bool use_bf16 = (ws_size >= need_bf16);

    // zero cnt+cur (adjacent)
    int zn = 2 * N;
    gin_zero_i<<<(zn + 255) / 256, 256, 0, stream>>>(cnt, zn);
    if (use_bf16) {
        int n4 = N * D / 4;
        gin_cvt_bf16<<<(n4 + 255) / 256, 256, 0, stream>>>((const float4*)x, (ushort4*)xb, n4);
    }
    gin_hist<<<(E + 255) / 256, 256, 0, stream>>>(ei, cnt, E);
    gin_scan1<<<nb, 256, 0, stream>>>(cnt, off, bsum, N);
    gin_scan2<<<1, 1024, 0, stream>>>(bsum, nb);
    gin_fill<<<(E + 255) / 256, 256, 0, stream>>>(ei, off, bsum, cur, bucket, E);
    if (use_bf16)
        gin_fused<1><<<(N + BM - 1) / BM, 256, 0, stream>>>(x, xb, eps, W1, b1, W2, b2,
                                                            off, cnt, bsum, bucket, out);
    else
        gin_fused<0><<<(N + BM - 1) / BM, 256, 0, stream>>>(x, xb, eps, W1, b1, W2, b2,
                                                            off, cnt, bsum, bucket, out);
}

// Round 4
// 291.438 us; speedup vs baseline: 9.6492x; 1.1253x over previous
//
#include <hip/hip_runtime.h>

typedef unsigned int uint;
typedef unsigned short ushort;
typedef __attribute__((ext_vector_type(8))) short short8v;
typedef __attribute__((ext_vector_type(4))) float f32x4;

#define D 128
#define BMG 32       // gather tile rows
#define LDH 136      // LDS row stride in ushorts (272 B = 17*16, b128-aligned, conflict-free)
#define SCAN_B 1024

// ---------- edge-index dtype hedge (int64 vs int32), wave-uniform ----------
__device__ __forceinline__ bool ei_is64(const int* ei32) {
    return ((ei32[1] | ei32[3] | ei32[5] | ei32[7]) == 0);
}
__device__ __forceinline__ float b2f(ushort u) { return __uint_as_float((uint)u << 16); }
__device__ __forceinline__ ushort f2b(float f) {   // RNE
    uint a = __float_as_uint(f);
    return (ushort)((a + 0x7fffu + ((a >> 16) & 1u)) >> 16);
}

// ---------------- prep: x -> bf16 copy + W1/W2 -> bf16 transpose ----------------
__global__ __launch_bounds__(256) void gin_prep(
    const float4* __restrict__ x4, ushort4* __restrict__ xb4, int n4,
    const float* __restrict__ W1, const float* __restrict__ W2,
    ushort* __restrict__ w1t, ushort* __restrict__ w2t, int nxb)
{
    int bid = blockIdx.x;
    if (bid < nxb) {
        int i = bid * 256 + threadIdx.x;
        if (i < n4) {
            float4 v = x4[i];
            ushort4 o;
            o.x = f2b(v.x); o.y = f2b(v.y); o.z = f2b(v.z); o.w = f2b(v.w);
            xb4[i] = o;
        }
    } else {
        int idx = (bid - nxb) * 256 + threadIdx.x;   // [0, 2*128*128)
        int which = idx >> 14;
        int rem   = idx & 16383;                     // n*128 + k
        int k = rem & 127, n = rem >> 7;
        const float* W = which ? W2 : W1;
        ushort* WT = which ? w2t : w1t;
        WT[rem] = f2b(W[k * D + n]);                 // WT[n][k] = W[k][n]
    }
}

// ---------------- histogram of destinations ----------------
__global__ __launch_bounds__(256) void gin_hist(const void* __restrict__ ei_raw,
                                                int* __restrict__ cnt, int E) {
    int e = blockIdx.x * 256 + threadIdx.x;
    if (e >= E) return;
    const int* ei32 = (const int*)ei_raw;
    const long long* ei64 = (const long long*)ei_raw;
    int dst = ei_is64(ei32) ? (int)ei64[e] : ei32[e];
    atomicAdd(&cnt[dst], 1);
}

// ---------------- per-1024-chunk exclusive scan (partial) ----------------
__global__ __launch_bounds__(256) void gin_scan1(const int* __restrict__ cnt,
                                                 int* __restrict__ off,
                                                 int* __restrict__ bsum, int N) {
    __shared__ int ts[256];
    int tid = threadIdx.x;
    int base = blockIdx.x * SCAN_B + tid * 4;
    int v[4]; int s = 0;
    #pragma unroll
    for (int j = 0; j < 4; ++j) { int idx = base + j; v[j] = (idx < N) ? cnt[idx] : 0; s += v[j]; }
    ts[tid] = s;
    __syncthreads();
    for (int d = 1; d < 256; d <<= 1) {
        int t = (tid >= d) ? ts[tid - d] : 0;
        __syncthreads();
        ts[tid] += t;
        __syncthreads();
    }
    int excl = ts[tid] - s;
    if (tid == 255) bsum[blockIdx.x] = ts[255];
    int run = excl;
    #pragma unroll
    for (int j = 0; j < 4; ++j) { int idx = base + j; if (idx < N) off[idx] = run; run += v[j]; }
}

// ---------------- parallel scan of chunk sums (one block) ----------------
__global__ __launch_bounds__(1024) void gin_scan2(int* __restrict__ bsum, int nb) {
    __shared__ int ts[1024];
    int t = threadIdx.x;
    if (nb <= 1024) {
        int v = (t < nb) ? bsum[t] : 0;
        ts[t] = v;
        __syncthreads();
        for (int d = 1; d < 1024; d <<= 1) {
            int u = (t >= d) ? ts[t - d] : 0;
            __syncthreads();
            ts[t] += u;
            __syncthreads();
        }
        if (t < nb) bsum[t] = ts[t] - v;   // exclusive
    } else if (t == 0) {
        int run = 0;
        for (int b = 0; b < nb; ++b) { int v = bsum[b]; bsum[b] = run; run += v; }
    }
}

// ---------------- fill buckets with source indices ----------------
__global__ __launch_bounds__(256) void gin_fill(const void* __restrict__ ei_raw,
                                                const int* __restrict__ off,
                                                const int* __restrict__ bsum,
                                                int* __restrict__ cur,
                                                int* __restrict__ bucket, int E) {
    int e = blockIdx.x * 256 + threadIdx.x;
    if (e >= E) return;
    const int* ei32 = (const int*)ei_raw;
    const long long* ei64 = (const long long*)ei_raw;
    int dst, src;
    if (ei_is64(ei32)) { dst = (int)ei64[e]; src = (int)ei64[E + e]; }
    else               { dst = ei32[e];      src = ei32[E + e]; }
    int p = atomicAdd(&cur[dst], 1);
    bucket[off[dst] + bsum[dst >> 10] + p] = src;
}

// ---------------- gather one row: (1+eps)*x[node] + sum x[src] ----------------
template<int BF16>
__device__ __forceinline__ float4 gather_row(
    const float* __restrict__ x, const ushort4* __restrict__ xr,
    const int* __restrict__ bucket, long long node, int lane,
    int start, int deg, float epsv)
{
    float4 acc = reinterpret_cast<const float4*>(x + node * D)[lane];
    acc.x *= epsv; acc.y *= epsv; acc.z *= epsv; acc.w *= epsv;
    int j = 0;
    if (BF16) {
        for (; j + 8 <= deg; j += 8) {
            int s[8];
            #pragma unroll
            for (int q = 0; q < 8; ++q) s[q] = bucket[start + j + q];
            ushort4 r[8];
            #pragma unroll
            for (int q = 0; q < 8; ++q) r[q] = xr[(long long)s[q] * 32 + lane];
            #pragma unroll
            for (int q = 0; q < 8; ++q) {
                acc.x += b2f(r[q].x); acc.y += b2f(r[q].y);
                acc.z += b2f(r[q].z); acc.w += b2f(r[q].w);
            }
        }
        for (; j < deg; ++j) {
            int s = bucket[start + j];
            ushort4 r = xr[(long long)s * 32 + lane];
            acc.x += b2f(r.x); acc.y += b2f(r.y); acc.z += b2f(r.z); acc.w += b2f(r.w);
        }
    } else {
        for (; j + 4 <= deg; j += 4) {
            int s0 = bucket[start + j + 0];
            int s1 = bucket[start + j + 1];
            int s2 = bucket[start + j + 2];
            int s3 = bucket[start + j + 3];
            float4 v0 = reinterpret_cast<const float4*>(x + (long long)s0 * D)[lane];
            float4 v1 = reinterpret_cast<const float4*>(x + (long long)s1 * D)[lane];
            float4 v2 = reinterpret_cast<const float4*>(x + (long long)s2 * D)[lane];
            float4 v3 = reinterpret_cast<const float4*>(x + (long long)s3 * D)[lane];
            acc.x += (v0.x + v1.x) + (v2.x + v3.x);
            acc.y += (v0.y + v1.y) + (v2.y + v3.y);
            acc.z += (v0.z + v1.z) + (v2.z + v3.z);
            acc.w += (v0.w + v1.w) + (v2.w + v3.w);
        }
        for (; j < deg; ++j) {
            int s = bucket[start + j];
            float4 v = reinterpret_cast<const float4*>(x + (long long)s * D)[lane];
            acc.x += v.x; acc.y += v.y; acc.z += v.z; acc.w += v.w;
        }
    }
    return acc;
}

// ---------------- split-mode gather: write Z (bf16) to workspace ----------------
__global__ __launch_bounds__(256, 8) void gin_gather(
    const float* __restrict__ x, const ushort* __restrict__ xb,
    const float* __restrict__ epsp,
    const int* __restrict__ off, const int* __restrict__ cnt,
    const int* __restrict__ bsum, const int* __restrict__ bucket,
    ushort* __restrict__ zb, int N)
{
    const int tid  = threadIdx.x;
    const int lane = tid & 31;
    const int grp  = tid >> 5;
    const long long n0 = (long long)blockIdx.x * BMG;
    const float epsv = 1.0f + epsp[0];
    const ushort4* xr = (const ushort4*)xb;
    for (int rr = grp; rr < BMG; rr += 8) {
        long long node = n0 + rr;
        if (node >= N) break;
        int start = off[node] + bsum[node >> 10];
        int deg   = cnt[node];
        float4 a = gather_row<1>(x, xr, bucket, node, lane, start, deg, epsv);
        ushort4 o;
        o.x = f2b(a.x); o.y = f2b(a.y); o.z = f2b(a.z); o.w = f2b(a.w);
        ((ushort4*)zb)[node * 32 + lane] = o;
    }
}

// ---------------- MFMA MLP over S (MT m-tiles of 16 rows), 4 waves ----------------
// mfma_f32_16x16x32_bf16 layouts: A row=l&15, k=(l>>4)*8+j (contiguous 8);
// B col=l&15, same k; C/D col=l&15, row=(l>>4)*4+reg (m89-verified).
template<int MT>
__device__ __forceinline__ void mlp_mfma(
    ushort* S, const ushort* __restrict__ w1t, const ushort* __restrict__ w2t,
    const float* __restrict__ b1, const float* __restrict__ b2,
    float* __restrict__ out, long long n0, int N, int tid)
{
    const int w   = tid >> 6;     // wave 0..3  -> n-tiles {2w, 2w+1}
    const int l   = tid & 63;
    const int c16 = l & 15;
    const int g   = l >> 4;
    const int n2a = 2 * w, n2b = 2 * w + 1;

    f32x4 acc[MT][2];
    {
        float bva = b1[n2a * 16 + c16];
        float bvb = b1[n2b * 16 + c16];
        #pragma unroll
        for (int m = 0; m < MT; ++m) {
            acc[m][0] = (f32x4){bva, bva, bva, bva};
            acc[m][1] = (f32x4){bvb, bvb, bvb, bvb};
        }
    }
    #pragma unroll
    for (int ks = 0; ks < 4; ++ks) {
        short8v a[MT];
        #pragma unroll
        for (int m = 0; m < MT; ++m)
            a[m] = *(const short8v*)&S[(m * 16 + c16) * LDH + ks * 32 + g * 8];
        short8v bA = *(const short8v*)&w1t[(n2a * 16 + c16) * D + ks * 32 + g * 8];
        short8v bB = *(const short8v*)&w1t[(n2b * 16 + c16) * D + ks * 32 + g * 8];
        #pragma unroll
        for (int m = 0; m < MT; ++m) {
            acc[m][0] = __builtin_amdgcn_mfma_f32_16x16x32_bf16(a[m], bA, acc[m][0], 0, 0, 0);
            acc[m][1] = __builtin_amdgcn_mfma_f32_16x16x32_bf16(a[m], bB, acc[m][1], 0, 0, 0);
        }
    }
    __syncthreads();   // all Z reads complete before H overwrite
    #pragma unroll
    for (int m = 0; m < MT; ++m) {
        #pragma unroll
        for (int ns = 0; ns < 2; ++ns) {
            int coln = (2 * w + ns) * 16 + c16;
            #pragma unroll
            for (int r = 0; r < 4; ++r) {
                float h = fmaxf(acc[m][ns][r], 0.f);
                S[(m * 16 + g * 4 + r) * LDH + coln] = f2b(h);
            }
        }
    }
    __syncthreads();
    {
        float bva = b2[n2a * 16 + c16];
        float bvb = b2[n2b * 16 + c16];
        #pragma unroll
        for (int m = 0; m < MT; ++m) {
            acc[m][0] = (f32x4){bva, bva, bva, bva};
            acc[m][1] = (f32x4){bvb, bvb, bvb, bvb};
        }
    }
    #pragma unroll
    for (int ks = 0; ks < 4; ++ks) {
        short8v a[MT];
        #pragma unroll
        for (int m = 0; m < MT; ++m)
            a[m] = *(const short8v*)&S[(m * 16 + c16) * LDH + ks * 32 + g * 8];
        short8v bA = *(const short8v*)&w2t[(n2a * 16 + c16) * D + ks * 32 + g * 8];
        short8v bB = *(const short8v*)&w2t[(n2b * 16 + c16) * D + ks * 32 + g * 8];
        #pragma unroll
        for (int m = 0; m < MT; ++m) {
            acc[m][0] = __builtin_amdgcn_mfma_f32_16x16x32_bf16(a[m], bA, acc[m][0], 0, 0, 0);
            acc[m][1] = __builtin_amdgcn_mfma_f32_16x16x32_bf16(a[m], bB, acc[m][1], 0, 0, 0);
        }
    }
    #pragma unroll
    for (int m = 0; m < MT; ++m) {
        #pragma unroll
        for (int ns = 0; ns < 2; ++ns) {
            long long coln = (2 * w + ns) * 16 + c16;
            #pragma unroll
            for (int r = 0; r < 4; ++r) {
                long long row = n0 + m * 16 + g * 4 + r;
                if (row < N) out[row * D + coln] = acc[m][ns][r];
            }
        }
    }
}

// ---------------- split-mode MLP: 64 rows/block ----------------
__global__ __launch_bounds__(256, 4) void gin_mlp(
    const ushort* __restrict__ zb, const ushort* __restrict__ w1t,
    const ushort* __restrict__ w2t, const float* __restrict__ b1,
    const float* __restrict__ b2, float* __restrict__ out, int N)
{
    __shared__ ushort S[64 * LDH];
    const int tid = threadIdx.x;
    const long long n0 = (long long)blockIdx.x * 64;
    for (int c = tid; c < 64 * 16; c += 256) {
        int row = c >> 4, cc = c & 15;
        uint4 v = ((const uint4*)(zb + (n0 + row) * D))[cc];
        *(uint4*)&S[row * LDH + cc * 8] = v;
    }
    __syncthreads();
    mlp_mfma<4>(S, w1t, w2t, b1, b2, out, n0, N, tid);
}

// ---------------- fused mode: gather -> LDS -> MFMA MLP ----------------
template<int BF16>
__global__ __launch_bounds__(256, 4) void gin_fused_mfma(
    const float* __restrict__ x, const ushort* __restrict__ xb,
    const float* __restrict__ epsp,
    const int* __restrict__ off, const int* __restrict__ cnt,
    const int* __restrict__ bsum, const int* __restrict__ bucket,
    const ushort* __restrict__ w1t, const ushort* __restrict__ w2t,
    const float* __restrict__ b1, const float* __restrict__ b2,
    float* __restrict__ out, int N)
{
    __shared__ ushort S[BMG * LDH];
    const int tid  = threadIdx.x;
    const int lane = tid & 31;
    const int grp  = tid >> 5;
    const long long n0 = (long long)blockIdx.x * BMG;
    const float epsv = 1.0f + epsp[0];
    const ushort4* xr = (const ushort4*)xb;
    for (int rr = grp; rr < BMG; rr += 8) {
        long long node = n0 + rr;
        if (node >= N) break;
        int start = off[node] + bsum[node >> 10];
        int deg   = cnt[node];
        float4 a = gather_row<BF16>(x, xr, bucket, node, lane, start, deg, epsv);
        ushort4 o;
        o.x = f2b(a.x); o.y = f2b(a.y); o.z = f2b(a.z); o.w = f2b(a.w);
        *(ushort4*)&S[rr * LDH + lane * 4] = o;
    }
    __syncthreads();
    mlp_mfma<2>(S, w1t, w2t, b1, b2, out, n0, N, tid);
}

extern "C" void kernel_launch(void* const* d_in, const int* in_sizes, int n_in,
                              void* d_out, int out_size, void* d_ws, size_t ws_size,
                              hipStream_t stream) {
    const float* x   = (const float*)d_in[0];
    const void*  ei  = d_in[1];
    const float* eps = (const float*)d_in[3];
    const float* W1  = (const float*)d_in[4];
    const float* b1  = (const float*)d_in[5];
    const float* W2  = (const float*)d_in[6];
    const float* b2  = (const float*)d_in[7];
    float* out = (float*)d_out;

    const int N = in_sizes[0] / D;   // 100000
    const int E = in_sizes[1] / 2;   // 1600000
    const int nb = (N + SCAN_B - 1) / SCAN_B;
    const int nb_pad = (nb + 255) & ~255;
    const long long Nr = ((long long)N + 63) & ~63LL;

    // ws layout: cnt[N] cur[N] off[N] bsum[nb_pad] bucket[E] | xb | w1t | w2t | zb
    size_t base   = ((size_t)3 * N + nb_pad + E) * sizeof(int);
    size_t xb_off = (base + 15) & ~(size_t)15;
    size_t w1_off = xb_off + (size_t)N * D * sizeof(ushort);
    size_t w2_off = w1_off + (size_t)D * D * sizeof(ushort);
    size_t zb_off = w2_off + (size_t)D * D * sizeof(ushort);
    size_t need_fused = zb_off;                                  // bf16 fused
    size_t need_split = zb_off + (size_t)Nr * D * sizeof(ushort);// + Z buffer
    size_t need_min   = xb_off + 2 * (size_t)D * D * sizeof(ushort); // fp32 fused (weights only)

    if (ws_size < need_min) return;   // cannot happen per prior rounds

    int* cnt    = (int*)d_ws;
    int* cur    = cnt + N;
    int* off    = cur + N;
    int* bsum   = off + N;
    int* bucket = bsum + nb_pad;
    const bool has_bf16  = (ws_size >= need_fused);
    const bool has_split = (ws_size >= need_split);
    ushort* xb, *w1t, *w2t, *zb;
    if (has_bf16) {
        xb  = (ushort*)((char*)d_ws + xb_off);
        w1t = (ushort*)((char*)d_ws + w1_off);
        w2t = (ushort*)((char*)d_ws + w2_off);
        zb  = (ushort*)((char*)d_ws + zb_off);
    } else {
        xb  = nullptr;
        w1t = (ushort*)((char*)d_ws + xb_off);
        w2t = w1t + D * D;
        zb  = nullptr;
    }

    hipMemsetAsync(cnt, 0, (size_t)2 * N * sizeof(int), stream);

    const int n4  = has_bf16 ? (N * D / 4) : 0;
    const int nxb = has_bf16 ? ((n4 + 255) / 256) : 0;
    gin_prep<<<nxb + 128, 256, 0, stream>>>((const float4*)x, (ushort4*)xb, n4,
                                            W1, W2, w1t, w2t, nxb);
    gin_hist<<<(E + 255) / 256, 256, 0, stream>>>(ei, cnt, E);
    gin_scan1<<<nb, 256, 0, stream>>>(cnt, off, bsum, N);
    gin_scan2<<<1, 1024, 0, stream>>>(bsum, nb);
    gin_fill<<<(E + 255) / 256, 256, 0, stream>>>(ei, off, bsum, cur, bucket, E);

    const int gblocks = (N + BMG - 1) / BMG;
    if (has_split) {
        gin_gather<<<gblocks, 256, 0, stream>>>(x, xb, eps, off, cnt, bsum, bucket, zb, N);
        gin_mlp<<<(int)((N + 63) / 64), 256, 0, stream>>>(zb, w1t, w2t, b1, b2, out, N);
    } else if (has_bf16) {
        gin_fused_mfma<1><<<gblocks, 256, 0, stream>>>(x, xb, eps, off, cnt, bsum, bucket,
                                                       w1t, w2t, b1, b2, out, N);
    } else {
        gin_fused_mfma<0><<<gblocks, 256, 0, stream>>>(x, xb, eps, off, cnt, bsum, bucket,
                                                       w1t, w2t, b1, b2, out, N);
    }
}